// Round 1
// baseline (5548.291 us; speedup 1.0000x reference)
//
#include <hip/hip_runtime.h>
#include <hip/hip_bf16.h>
#include <math.h>

// Problem constants
#define BB   2048
#define LL   60
#define DD   80
#define HH   8
#define HDD  10
#define NLNUM 3
#define NLOC 1187
#define DFF  160
#define IN_DIM 138   // 80 + 24 + 16 + 16 + 2
#define RELN 119     // 2*L - 1

// ---------------------------------------------------------------------------
// K1: embedding gather + input projection (138->80) + LayerNorm + pos_emb
// one block per token, 128 threads (80 active for outputs)
// ---------------------------------------------------------------------------
__global__ __launch_bounds__(128) void k_embed(
    const int* __restrict__ loc_seq, const int* __restrict__ user_seq,
    const int* __restrict__ wk_seq, const int* __restrict__ sm_seq,
    const int* __restrict__ dur_seq, const int* __restrict__ diff_seq,
    const float* __restrict__ loc_table, const float* __restrict__ user_table,
    const float* __restrict__ wk_table, const float* __restrict__ hr_table,
    const float* __restrict__ in_w, const float* __restrict__ in_b,
    const float* __restrict__ in_g, const float* __restrict__ in_be,
    const float* __restrict__ pos_emb, float* __restrict__ x) {
  int tok = blockIdx.x;            // b*LL + t
  int t = tok % LL;
  int b = tok / LL;
  int tid = threadIdx.x;

  __shared__ float vin[IN_DIM];
  __shared__ float red[128];
  __shared__ float red2[128];

  int loc = loc_seq[tok];
  int usr = user_seq[b * LL];      // user_seq[:, 0]
  int wk  = wk_seq[tok];
  int hr  = sm_seq[tok] / 60; hr = min(max(hr, 0), 23);
  float dif = (float)diff_seq[tok] / 10.0f;
  float dur = (float)dur_seq[tok] / 300.0f;

  for (int i = tid; i < IN_DIM; i += 128) {
    float v;
    if (i < 80)        v = loc_table[(size_t)loc * 80 + i];
    else if (i < 104)  v = user_table[usr * 24 + (i - 80)];
    else if (i < 120)  v = wk_table[wk * 16 + (i - 104)];
    else if (i < 136)  v = hr_table[hr * 16 + (i - 120)];
    else if (i == 136) v = dif;
    else               v = dur;
    vin[i] = v;
  }
  __syncthreads();

  float acc = 0.0f;
  if (tid < DD) {
    acc = in_b[tid];
    for (int i = 0; i < IN_DIM; i++) acc += vin[i] * in_w[i * DD + tid];
  }
  red[tid]  = (tid < DD) ? acc : 0.0f;
  red2[tid] = (tid < DD) ? acc * acc : 0.0f;
  __syncthreads();
  for (int s = 64; s > 0; s >>= 1) {
    if (tid < s) { red[tid] += red[tid + s]; red2[tid] += red2[tid + s]; }
    __syncthreads();
  }
  float mean = red[0] / DD;
  float var  = fmaxf(red2[0] / DD - mean * mean, 0.0f);
  float rstd = rsqrtf(var + 1e-5f);
  if (tid < DD) {
    float y = (acc - mean) * rstd * in_g[tid] + in_be[tid] + pos_emb[t * DD + tid];
    x[(size_t)tok * DD + tid] = y;
  }
}

// ---------------------------------------------------------------------------
// K2: fused qkv + relative-position attention + softmax + o  (per (b,h) block)
// LDS: x tile (60x80), rel (119x10), qkv (3x60x10), scores (60x60)
// ---------------------------------------------------------------------------
__global__ __launch_bounds__(256) void k_attn(
    const float* __restrict__ x, const int* __restrict__ loc_seq,
    const float* __restrict__ qkv_w,   // layer-offset (80 x 240)
    const float* __restrict__ rel_emb, // layer-offset (119 x 10)
    float* __restrict__ o) {
  int bh = blockIdx.x;
  int b = bh / HH, h = bh % HH;
  int tid = threadIdx.x;

  __shared__ float xs[LL * DD];        // 4800
  __shared__ float rel[RELN * HDD];    // 1190
  __shared__ float qkvs[3 * LL * HDD]; // 1800: [s][r][d]
  __shared__ float sc[LL * LL];        // 3600
  __shared__ float msk[LL];

  const float* xb = x + (size_t)b * LL * DD;
  for (int i = tid; i < LL * DD; i += 256) xs[i] = xb[i];
  for (int i = tid; i < RELN * HDD; i += 256) rel[i] = rel_emb[i];
  if (tid < LL) msk[tid] = (loc_seq[b * LL + tid] == 0) ? 1.0f : 0.0f;
  __syncthreads();

  // qkv for this head: col = s*80 + h*10 + d
  for (int idx = tid; idx < 3 * LL * HDD; idx += 256) {
    int s = idx / (LL * HDD);
    int r = (idx / HDD) % LL;
    int d = idx % HDD;
    int col = s * 80 + h * HDD + d;
    const float* wcol = qkv_w + col;
    const float* xr = xs + r * DD;
    float acc = 0.0f;
    for (int i = 0; i < DD; i++) acc += xr[i] * wcol[i * 240];
    qkvs[idx] = acc;   // layout matches s*600 + r*10 + d
  }
  __syncthreads();

  const float* qs = qkvs;
  const float* ks = qkvs + LL * HDD;
  const float* vs = qkvs + 2 * LL * HDD;
  const float scale = 0.31622776601683794f;  // 1/sqrt(10)

  for (int idx = tid; idx < LL * LL; idx += 256) {
    int i = idx / LL, j = idx % LL;
    const float* qi = qs + i * HDD;
    const float* kj = ks + j * HDD;
    const float* rr = rel + (j - i + LL - 1) * HDD;
    float acc = 0.0f;
    for (int d = 0; d < HDD; d++) acc += qi[d] * (kj[d] + rr[d]);
    acc *= scale;
    if (msk[j] != 0.0f) acc = -1e30f;
    sc[idx] = acc;
  }
  __syncthreads();

  // softmax per row: 4 waves, lanes = keys
  int wid = tid >> 6, lane = tid & 63;
  for (int i = wid; i < LL; i += 4) {
    float v = (lane < LL) ? sc[i * LL + lane] : -1e30f;
    float m = v;
    for (int s = 32; s > 0; s >>= 1) m = fmaxf(m, __shfl_xor(m, s));
    float e = (lane < LL) ? __expf(v - m) : 0.0f;
    float ssum = e;
    for (int s = 32; s > 0; s >>= 1) ssum += __shfl_xor(ssum, s);
    if (lane < LL) sc[i * LL + lane] = e / ssum;
  }
  __syncthreads();

  // o = a @ v, scattered into [B,L,80] at head offset
  for (int idx = tid; idx < LL * HDD; idx += 256) {
    int i = idx / HDD, d = idx % HDD;
    const float* ai = sc + i * LL;
    float acc = 0.0f;
    for (int j = 0; j < LL; j++) acc += ai[j] * vs[j * HDD + d];
    o[((size_t)b * LL + i) * DD + h * HDD + d] = acc;
  }
}

// ---------------------------------------------------------------------------
// K3: x = LN(x + o @ proj_w + proj_b)   one block per token, 128 threads
// ---------------------------------------------------------------------------
__global__ __launch_bounds__(128) void k_proj_ln(
    const float* __restrict__ o, const float* __restrict__ proj_w,
    const float* __restrict__ proj_b, const float* __restrict__ n1_g,
    const float* __restrict__ n1_b, float* __restrict__ x) {
  int tok = blockIdx.x, tid = threadIdx.x;
  __shared__ float orow[DD];
  __shared__ float red[128], red2[128];
  if (tid < DD) orow[tid] = o[(size_t)tok * DD + tid];
  __syncthreads();
  float acc = 0.0f;
  if (tid < DD) {
    acc = proj_b[tid];
    for (int i = 0; i < DD; i++) acc += orow[i] * proj_w[i * DD + tid];
    acc += x[(size_t)tok * DD + tid];
  }
  red[tid]  = (tid < DD) ? acc : 0.0f;
  red2[tid] = (tid < DD) ? acc * acc : 0.0f;
  __syncthreads();
  for (int s = 64; s > 0; s >>= 1) {
    if (tid < s) { red[tid] += red[tid + s]; red2[tid] += red2[tid + s]; }
    __syncthreads();
  }
  float mean = red[0] / DD;
  float var  = fmaxf(red2[0] / DD - mean * mean, 0.0f);
  float rstd = rsqrtf(var + 1e-5f);
  if (tid < DD)
    x[(size_t)tok * DD + tid] = (acc - mean) * rstd * n1_g[tid] + n1_b[tid];
}

// ---------------------------------------------------------------------------
// K4: f = gelu(x@w1+b1)@w2+b2 ; x = LN(x+f)   one block per token, 256 threads
// ---------------------------------------------------------------------------
__global__ __launch_bounds__(256) void k_ffn_ln(
    const float* __restrict__ w1, const float* __restrict__ b1,
    const float* __restrict__ w2, const float* __restrict__ b2,
    const float* __restrict__ n2_g, const float* __restrict__ n2_b,
    float* __restrict__ x) {
  int tok = blockIdx.x, tid = threadIdx.x;
  __shared__ float xr[DD];
  __shared__ float hbuf[DFF];
  __shared__ float red[256], red2[256];
  if (tid < DD) xr[tid] = x[(size_t)tok * DD + tid];
  __syncthreads();
  if (tid < DFF) {
    float a = b1[tid];
    for (int i = 0; i < DD; i++) a += xr[i] * w1[i * DFF + tid];
    hbuf[tid] = 0.5f * a * (1.0f + erff(a * 0.70710678118654752f));  // exact gelu
  }
  __syncthreads();
  float acc = 0.0f;
  if (tid < DD) {
    acc = b2[tid];
    for (int i = 0; i < DFF; i++) acc += hbuf[i] * w2[i * DD + tid];
    acc += xr[tid];
  }
  red[tid]  = (tid < DD) ? acc : 0.0f;
  red2[tid] = (tid < DD) ? acc * acc : 0.0f;
  __syncthreads();
  for (int s = 128; s > 0; s >>= 1) {
    if (tid < s) { red[tid] += red[tid + s]; red2[tid] += red2[tid + s]; }
    __syncthreads();
  }
  float mean = red[0] / DD;
  float var  = fmaxf(red2[0] / DD - mean * mean, 0.0f);
  float rstd = rsqrtf(var + 1e-5f);
  if (tid < DD)
    x[(size_t)tok * DD + tid] = (acc - mean) * rstd * n2_g[tid] + n2_b[tid];
}

// ---------------------------------------------------------------------------
// K5: final LN at gathered position + fnorm + h1=gelu(final@pr_w1+pr_b1)
// one block per batch element, 128 threads
// ---------------------------------------------------------------------------
__global__ __launch_bounds__(128) void k_final(
    const float* __restrict__ x, const int* __restrict__ seq_len,
    const float* __restrict__ fn_g, const float* __restrict__ fn_b,
    const float* __restrict__ pr_w1, const float* __restrict__ pr_b1,
    float* __restrict__ fnorm, float* __restrict__ h1) {
  int b = blockIdx.x, tid = threadIdx.x;
  __shared__ float red[128], red2[128];
  __shared__ float fbuf[DD];
  int t = seq_len[b] - 1; t = min(max(t, 0), LL - 1);
  float v = 0.0f;
  if (tid < DD) v = x[((size_t)b * LL + t) * DD + tid];
  red[tid]  = (tid < DD) ? v : 0.0f;
  red2[tid] = (tid < DD) ? v * v : 0.0f;
  __syncthreads();
  for (int s = 64; s > 0; s >>= 1) {
    if (tid < s) { red[tid] += red[tid + s]; red2[tid] += red2[tid + s]; }
    __syncthreads();
  }
  float mean = red[0] / DD;
  float var  = fmaxf(red2[0] / DD - mean * mean, 0.0f);
  float rstd = rsqrtf(var + 1e-5f);
  float f = 0.0f;
  if (tid < DD) { f = (v - mean) * rstd * fn_g[tid] + fn_b[tid]; fbuf[tid] = f; }
  __syncthreads();
  red[tid] = (tid < DD) ? f * f : 0.0f;
  __syncthreads();
  for (int s = 64; s > 0; s >>= 1) {
    if (tid < s) red[tid] += red[tid + s];
    __syncthreads();
  }
  float rn = 1.0f / fmaxf(sqrtf(red[0]), 1e-12f);
  if (tid < DD) {
    fnorm[(size_t)b * DD + tid] = f * rn;
    float g = pr_b1[tid];
    for (int i = 0; i < DD; i++) g += fbuf[i] * pr_w1[i * DD + tid];
    h1[(size_t)b * DD + tid] = 0.5f * g * (1.0f + erff(g * 0.70710678118654752f));
  }
}

// ---------------------------------------------------------------------------
// K6: normalize proto rows  (one block per proto)
// ---------------------------------------------------------------------------
__global__ __launch_bounds__(128) void k_pnorm(
    const float* __restrict__ protos, float* __restrict__ pnorm) {
  int c = blockIdx.x, tid = threadIdx.x;
  __shared__ float red[128];
  float v = 0.0f;
  if (tid < DD) v = protos[(size_t)c * DD + tid];
  red[tid] = (tid < DD) ? v * v : 0.0f;
  __syncthreads();
  for (int s = 64; s > 0; s >>= 1) {
    if (tid < s) red[tid] += red[tid + s];
    __syncthreads();
  }
  float rn = 1.0f / fmaxf(sqrtf(red[0]), 1e-12f);
  if (tid < DD) pnorm[(size_t)c * DD + tid] = v * rn;
}

// ---------------------------------------------------------------------------
// K7: logits = (0.5*(h1@pr_w2+pr_b2) + 7.5*(fnorm@pnorm^T)) / clip(temp,.5,3)
// one block = one b x 256 classes ; grid = B * ceil(NLOC/256)
// ---------------------------------------------------------------------------
__global__ __launch_bounds__(256) void k_logits(
    const float* __restrict__ h1, const float* __restrict__ fnorm,
    const float* __restrict__ pr_w2, const float* __restrict__ pr_b2,
    const float* __restrict__ pnorm, const float* __restrict__ temp,
    float* __restrict__ out) {
  int b = blockIdx.x / 5;
  int cb = blockIdx.x % 5;
  int tid = threadIdx.x;
  int c = cb * 256 + tid;
  __shared__ float h1s[DD], fns[DD];
  if (tid < DD) { h1s[tid] = h1[(size_t)b * DD + tid]; fns[tid] = fnorm[(size_t)b * DD + tid]; }
  __syncthreads();
  if (c < NLOC) {
    float a1 = pr_b2[c];
    for (int k = 0; k < DD; k++) a1 += h1s[k] * pr_w2[k * NLOC + c];
    float a2 = 0.0f;
    const float* pn = pnorm + (size_t)c * DD;
    for (int k = 0; k < DD; k++) a2 += fns[k] * pn[k];
    float tt = fminf(fmaxf(temp[0], 0.5f), 3.0f);
    out[(size_t)b * NLOC + c] = (0.5f * a1 + 7.5f * a2) / tt;
  }
}

// ---------------------------------------------------------------------------
extern "C" void kernel_launch(void* const* d_in, const int* in_sizes, int n_in,
                              void* d_out, int out_size, void* d_ws, size_t ws_size,
                              hipStream_t stream) {
  const int* loc_seq   = (const int*)d_in[0];
  const int* user_seq  = (const int*)d_in[1];
  const int* wk_seq    = (const int*)d_in[2];
  const int* sm_seq    = (const int*)d_in[3];
  const int* dur_seq   = (const int*)d_in[4];
  const int* diff_seq  = (const int*)d_in[5];
  const int* seq_len   = (const int*)d_in[6];
  const float* loc_table = (const float*)d_in[7];
  const float* user_table= (const float*)d_in[8];
  const float* wk_table  = (const float*)d_in[9];
  const float* hr_table  = (const float*)d_in[10];
  const float* in_w   = (const float*)d_in[11];
  const float* in_b   = (const float*)d_in[12];
  const float* in_g   = (const float*)d_in[13];
  const float* in_be  = (const float*)d_in[14];
  const float* pos_emb= (const float*)d_in[15];
  const float* qkv_w  = (const float*)d_in[16];
  const float* proj_w = (const float*)d_in[17];
  const float* proj_b = (const float*)d_in[18];
  const float* rel_emb= (const float*)d_in[19];
  const float* n1_g   = (const float*)d_in[20];
  const float* n1_b   = (const float*)d_in[21];
  const float* ffn_w1 = (const float*)d_in[22];
  const float* ffn_b1 = (const float*)d_in[23];
  const float* ffn_w2 = (const float*)d_in[24];
  const float* ffn_b2 = (const float*)d_in[25];
  const float* n2_g   = (const float*)d_in[26];
  const float* n2_b   = (const float*)d_in[27];
  const float* fn_g   = (const float*)d_in[28];
  const float* fn_b   = (const float*)d_in[29];
  const float* pr_w1  = (const float*)d_in[30];
  const float* pr_b1  = (const float*)d_in[31];
  const float* pr_w2  = (const float*)d_in[32];
  const float* pr_b2  = (const float*)d_in[33];
  const float* protos = (const float*)d_in[34];
  const float* temp   = (const float*)d_in[35];
  float* out = (float*)d_out;

  // workspace layout
  float* x     = (float*)d_ws;                  // B*L*80
  float* o     = x + (size_t)BB * LL * DD;      // B*L*80
  float* fnorm = o + (size_t)BB * LL * DD;      // B*80
  float* h1    = fnorm + (size_t)BB * DD;       // B*80
  float* pnorm = h1 + (size_t)BB * DD;          // NLOC*80

  k_embed<<<BB * LL, 128, 0, stream>>>(loc_seq, user_seq, wk_seq, sm_seq, dur_seq,
                                       diff_seq, loc_table, user_table, wk_table,
                                       hr_table, in_w, in_b, in_g, in_be, pos_emb, x);

  for (int l = 0; l < NLNUM; l++) {
    k_attn<<<BB * HH, 256, 0, stream>>>(x, loc_seq,
                                        qkv_w + (size_t)l * 80 * 240,
                                        rel_emb + (size_t)l * RELN * HDD, o);
    k_proj_ln<<<BB * LL, 128, 0, stream>>>(o, proj_w + (size_t)l * DD * DD,
                                           proj_b + (size_t)l * DD,
                                           n1_g + (size_t)l * DD,
                                           n1_b + (size_t)l * DD, x);
    k_ffn_ln<<<BB * LL, 256, 0, stream>>>(ffn_w1 + (size_t)l * DD * DFF,
                                          ffn_b1 + (size_t)l * DFF,
                                          ffn_w2 + (size_t)l * DFF * DD,
                                          ffn_b2 + (size_t)l * DD,
                                          n2_g + (size_t)l * DD,
                                          n2_b + (size_t)l * DD, x);
  }

  k_pnorm<<<NLOC, 128, 0, stream>>>(protos, pnorm);
  k_final<<<BB, 128, 0, stream>>>(x, seq_len, fn_g, fn_b, pr_w1, pr_b1, fnorm, h1);
  k_logits<<<BB * 5, 256, 0, stream>>>(h1, fnorm, pr_w2, pr_b2, pnorm, temp, out);
}

// Round 2
// 4643.618 us; speedup vs baseline: 1.1948x; 1.1948x over previous
//
#include <hip/hip_runtime.h>
#include <hip/hip_bf16.h>
#include <math.h>

#define BB   2048
#define LL   60
#define DD   80
#define HH   8
#define HDD  10
#define NLNUM 3
#define NLOC 1187
#define DFF  160
#define IN_DIM 138
#define RELN 119

// ---------------------------------------------------------------------------
// K1: embedding gather + input projection (138->80) + LayerNorm + pos_emb
// ---------------------------------------------------------------------------
__global__ __launch_bounds__(128) void k_embed(
    const int* __restrict__ loc_seq, const int* __restrict__ user_seq,
    const int* __restrict__ wk_seq, const int* __restrict__ sm_seq,
    const int* __restrict__ dur_seq, const int* __restrict__ diff_seq,
    const float* __restrict__ loc_table, const float* __restrict__ user_table,
    const float* __restrict__ wk_table, const float* __restrict__ hr_table,
    const float* __restrict__ in_w, const float* __restrict__ in_b,
    const float* __restrict__ in_g, const float* __restrict__ in_be,
    const float* __restrict__ pos_emb, float* __restrict__ x) {
  int tok = blockIdx.x;
  int t = tok % LL;
  int b = tok / LL;
  int tid = threadIdx.x;

  __shared__ __align__(16) float vin[IN_DIM];
  __shared__ float red[128];
  __shared__ float red2[128];

  int loc = loc_seq[tok];
  int usr = user_seq[b * LL];
  int wk  = wk_seq[tok];
  int hr  = sm_seq[tok] / 60; hr = min(max(hr, 0), 23);
  float dif = (float)diff_seq[tok] / 10.0f;
  float dur = (float)dur_seq[tok] / 300.0f;

  for (int i = tid; i < IN_DIM; i += 128) {
    float v;
    if (i < 80)        v = loc_table[(size_t)loc * 80 + i];
    else if (i < 104)  v = user_table[usr * 24 + (i - 80)];
    else if (i < 120)  v = wk_table[wk * 16 + (i - 104)];
    else if (i < 136)  v = hr_table[hr * 16 + (i - 120)];
    else if (i == 136) v = dif;
    else               v = dur;
    vin[i] = v;
  }
  __syncthreads();

  float acc = 0.0f;
  if (tid < DD) {
    acc = in_b[tid];
    for (int i = 0; i < IN_DIM; i++) acc += vin[i] * in_w[i * DD + tid];
  }
  red[tid]  = (tid < DD) ? acc : 0.0f;
  red2[tid] = (tid < DD) ? acc * acc : 0.0f;
  __syncthreads();
  for (int s = 64; s > 0; s >>= 1) {
    if (tid < s) { red[tid] += red[tid + s]; red2[tid] += red2[tid + s]; }
    __syncthreads();
  }
  float mean = red[0] / DD;
  float var  = fmaxf(red2[0] / DD - mean * mean, 0.0f);
  float rstd = rsqrtf(var + 1e-5f);
  if (tid < DD) {
    float y = (acc - mean) * rstd * in_g[tid] + in_be[tid] + pos_emb[t * DD + tid];
    x[(size_t)tok * DD + tid] = y;
  }
}

// ---------------------------------------------------------------------------
// K2a: qkv GEMM per batch row b: [60 x 80] @ [80 x 240] -> qkvo[b][c][t]
// 4x4 register tiles, b128 LDS reads both operands.
// ---------------------------------------------------------------------------
__global__ __launch_bounds__(256) void k_qkv(
    const float* __restrict__ x, const float* __restrict__ qkv_w,
    float* __restrict__ qkvo) {
  int b = blockIdx.x, tid = threadIdx.x;
  __shared__ __align__(16) float xs[LL * DD];   // [t][i]
  __shared__ __align__(16) float ws[DD * DD];   // [i][j] col-chunk of 80

  const float4* xb4 = (const float4*)(x + (size_t)b * LL * DD);
  float4* xs4 = (float4*)xs;
  for (int i = tid; i < LL * 20; i += 256) xs4[i] = xb4[i];
  float4* ws4 = (float4*)ws;

  for (int c0 = 0; c0 < 240; c0 += 80) {
    __syncthreads();
    for (int i = tid; i < 80 * 20; i += 256)
      ws4[i] = *(const float4*)(qkv_w + (i / 20) * 240 + c0 + (i % 20) * 4);
    __syncthreads();
    for (int slot = tid; slot < 300; slot += 256) {
      int tg = slot / 20, cg = slot % 20;
      int t0 = tg * 4;
      float acc[4][4] = {};
      #pragma unroll
      for (int iq = 0; iq < 20; iq++) {
        float4 xv[4], wv[4];
        #pragma unroll
        for (int dt = 0; dt < 4; dt++) xv[dt] = xs4[(t0 + dt) * 20 + iq];
        #pragma unroll
        for (int di = 0; di < 4; di++) wv[di] = ws4[(iq * 4 + di) * 20 + cg];
        #pragma unroll
        for (int dt = 0; dt < 4; dt++) {
          const float* xp = (const float*)&xv[dt];
          #pragma unroll
          for (int di = 0; di < 4; di++) {
            const float* wp = (const float*)&wv[di];
            #pragma unroll
            for (int dc = 0; dc < 4; dc++) acc[dt][dc] += xp[di] * wp[dc];
          }
        }
      }
      float* qb = qkvo + (size_t)b * 14400 + (size_t)(c0 + cg * 4) * 60 + t0;
      #pragma unroll
      for (int dc = 0; dc < 4; dc++)
        *(float4*)(qb + dc * 60) = make_float4(acc[0][dc], acc[1][dc], acc[2][dc], acc[3][dc]);
    }
  }
}

// ---------------------------------------------------------------------------
// K2b: attention per (b,h) reading precomputed qkv [b][c][t].
// Scores: 4x4-tiled 60x60x10 GEMM with rel folded in via transposed relT.
// ---------------------------------------------------------------------------
__global__ __launch_bounds__(256) void k_attn(
    const float* __restrict__ qkvo, const int* __restrict__ loc_seq,
    const float* __restrict__ rel_emb,   // layer ptr [119][10]
    float* __restrict__ o) {
  int bh = blockIdx.x;
  int b = bh >> 3, h = bh & 7;
  int tid = threadIdx.x;

  __shared__ __align__(16) float qs[HDD * 60];
  __shared__ __align__(16) float ks[HDD * 60];
  __shared__ __align__(16) float vs[HDD * 60];
  __shared__ __align__(16) float relT[HDD * 120];  // [d][p], stride 120
  __shared__ __align__(16) float sc[60 * 64];      // stride 64
  __shared__ float msk[60];

  const float4* src = (const float4*)(qkvo + (size_t)b * 14400);
  float4* q4 = (float4*)qs; float4* k4 = (float4*)ks; float4* v4 = (float4*)vs;
  for (int i = tid; i < 150; i += 256) {
    q4[i] = src[h * 150 + i];
    k4[i] = src[1200 + h * 150 + i];
    v4[i] = src[2400 + h * 150 + i];
  }
  for (int i = tid; i < RELN * HDD; i += 256) {
    int p = i / 10, d = i % 10;
    relT[d * 120 + p] = rel_emb[i];
  }
  if (tid < 60) msk[tid] = (loc_seq[b * LL + tid] == 0) ? 1.0f : 0.0f;
  __syncthreads();

  // scores
  if (tid < 225) {
    int ig = tid / 15, jg = tid % 15;
    int i0 = ig * 4, j0 = jg * 4;
    int w0 = j0 - i0 + 56;   // multiple of 4
    float acc[4][4] = {};
    #pragma unroll
    for (int d = 0; d < 10; d++) {
      float4 qv = *(const float4*)(qs + d * 60 + i0);
      float4 kv = *(const float4*)(ks + d * 60 + j0);
      float4 rA = *(const float4*)(relT + d * 120 + w0);
      float4 rB = *(const float4*)(relT + d * 120 + w0 + 4);
      float rr[8] = {rA.x, rA.y, rA.z, rA.w, rB.x, rB.y, rB.z, rB.w};
      const float* qp = (const float*)&qv;
      const float* kp = (const float*)&kv;
      #pragma unroll
      for (int di = 0; di < 4; di++)
        #pragma unroll
        for (int dj = 0; dj < 4; dj++)
          acc[di][dj] += qp[di] * (kp[dj] + rr[dj - di + 3]);
    }
    const float scale = 0.31622776601683794f;
    #pragma unroll
    for (int di = 0; di < 4; di++) {
      #pragma unroll
      for (int dj = 0; dj < 4; dj++) {
        float v = acc[di][dj] * scale;
        if (msk[j0 + dj] != 0.0f) v = -1e30f;
        acc[di][dj] = v;
      }
      *(float4*)(sc + (i0 + di) * 64 + j0) =
          make_float4(acc[di][0], acc[di][1], acc[di][2], acc[di][3]);
    }
  }
  __syncthreads();

  // softmax per row (wave per row)
  int wid = tid >> 6, lane = tid & 63;
  for (int i = wid; i < 60; i += 4) {
    float v = (lane < 60) ? sc[i * 64 + lane] : -3.0e38f;
    float m = v;
    #pragma unroll
    for (int s = 32; s > 0; s >>= 1) m = fmaxf(m, __shfl_xor(m, s));
    float e = (lane < 60) ? __expf(v - m) : 0.0f;
    float sum = e;
    #pragma unroll
    for (int s = 32; s > 0; s >>= 1) sum += __shfl_xor(sum, s);
    if (lane < 60) sc[i * 64 + lane] = e / sum;
  }
  __syncthreads();

  // O = A @ V^T : per (i-quad, d)
  if (tid < 150) {
    int ig = tid / 10, d = tid % 10;
    int i0 = ig * 4;
    float acc[4] = {0, 0, 0, 0};
    #pragma unroll
    for (int jq = 0; jq < 15; jq++) {
      float4 vv = *(const float4*)(vs + d * 60 + jq * 4);
      #pragma unroll
      for (int di = 0; di < 4; di++) {
        float4 av = *(const float4*)(sc + (i0 + di) * 64 + jq * 4);
        acc[di] += av.x * vv.x + av.y * vv.y + av.z * vv.z + av.w * vv.w;
      }
    }
    #pragma unroll
    for (int di = 0; di < 4; di++)
      o[((size_t)b * 60 + i0 + di) * 80 + h * 10 + d] = acc[di];
  }
}

// ---------------------------------------------------------------------------
// K3: x = LN(x + o @ proj_w + proj_b)  — 48 tokens/block, staged weights
// ---------------------------------------------------------------------------
__global__ __launch_bounds__(256) void k_proj_ln(
    const float* __restrict__ o, const float* __restrict__ proj_w,
    const float* __restrict__ proj_b, const float* __restrict__ g,
    const float* __restrict__ be, float* __restrict__ x) {
  int tok0 = blockIdx.x * 48, tid = threadIdx.x;
  __shared__ __align__(16) float os[48 * 80];
  __shared__ __align__(16) float ws[80 * 80];
  __shared__ float mstd[96];

  float4* os4 = (float4*)os;
  const float4* ob4 = (const float4*)(o + (size_t)tok0 * 80);
  for (int i = tid; i < 960; i += 256) os4[i] = ob4[i];
  float4* ws4 = (float4*)ws;
  for (int i = tid; i < 1600; i += 256)
    ws4[i] = *(const float4*)(proj_w + (i / 20) * 80 + (i % 20) * 4);
  __syncthreads();

  int tg = tid / 20, cg = tid % 20, t0 = tg * 4;
  float acc[4][4] = {};
  if (tid < 240) {
    #pragma unroll
    for (int iq = 0; iq < 20; iq++) {
      float4 xv[4], wv[4];
      #pragma unroll
      for (int dt = 0; dt < 4; dt++) xv[dt] = os4[(t0 + dt) * 20 + iq];
      #pragma unroll
      for (int di = 0; di < 4; di++) wv[di] = ws4[(iq * 4 + di) * 20 + cg];
      #pragma unroll
      for (int dt = 0; dt < 4; dt++) {
        const float* xp = (const float*)&xv[dt];
        #pragma unroll
        for (int di = 0; di < 4; di++) {
          const float* wp = (const float*)&wv[di];
          #pragma unroll
          for (int dc = 0; dc < 4; dc++) acc[dt][dc] += xp[di] * wp[dc];
        }
      }
    }
  }
  __syncthreads();   // os readers done; reuse os as y-buffer
  if (tid < 240) {
    float4 pb = *(const float4*)(proj_b + cg * 4);
    const float* pbp = (const float*)&pb;
    #pragma unroll
    for (int dt = 0; dt < 4; dt++) {
      float4 xr = *(const float4*)(x + (size_t)(tok0 + t0 + dt) * 80 + cg * 4);
      const float* xrp = (const float*)&xr;
      float4 out;
      out.x = acc[dt][0] + pbp[0] + xrp[0];
      out.y = acc[dt][1] + pbp[1] + xrp[1];
      out.z = acc[dt][2] + pbp[2] + xrp[2];
      out.w = acc[dt][3] + pbp[3] + xrp[3];
      os4[(t0 + dt) * 20 + cg] = out;
    }
  }
  __syncthreads();
  if (tid < 48) {
    float s = 0.0f, s2 = 0.0f;
    #pragma unroll
    for (int iq = 0; iq < 20; iq++) {
      float4 v = os4[tid * 20 + iq];
      s  += v.x + v.y + v.z + v.w;
      s2 += v.x * v.x + v.y * v.y + v.z * v.z + v.w * v.w;
    }
    float mean = s / 80.0f;
    float var  = fmaxf(s2 / 80.0f - mean * mean, 0.0f);
    mstd[tid] = mean; mstd[48 + tid] = rsqrtf(var + 1e-5f);
  }
  __syncthreads();
  for (int e = tid; e < 960; e += 256) {
    int t = e / 20, c4 = e % 20;
    float4 v = os4[e];
    float4 gg = *(const float4*)(g + c4 * 4);
    float4 bb = *(const float4*)(be + c4 * 4);
    float m = mstd[t], r = mstd[48 + t];
    float4 out;
    out.x = (v.x - m) * r * gg.x + bb.x;
    out.y = (v.y - m) * r * gg.y + bb.y;
    out.z = (v.z - m) * r * gg.z + bb.z;
    out.w = (v.w - m) * r * gg.w + bb.w;
    ((float4*)(x + (size_t)tok0 * 80))[e] = out;
  }
}

// ---------------------------------------------------------------------------
// K4a: H = gelu(X @ W1 + b1)  — 48 tokens/block
// ---------------------------------------------------------------------------
__global__ __launch_bounds__(256) void k_ffn1(
    const float* __restrict__ x, const float* __restrict__ w1,
    const float* __restrict__ b1, float* __restrict__ hb) {
  int tok0 = blockIdx.x * 48, tid = threadIdx.x;
  __shared__ __align__(16) float xs[48 * 80];
  __shared__ __align__(16) float ws[80 * 80];
  float4* xs4 = (float4*)xs;
  const float4* xb4 = (const float4*)(x + (size_t)tok0 * 80);
  for (int i = tid; i < 960; i += 256) xs4[i] = xb4[i];
  float4* ws4 = (float4*)ws;
  int tg = tid / 20, cg = tid % 20, t0 = tg * 4;

  for (int c0 = 0; c0 < 160; c0 += 80) {
    __syncthreads();
    for (int i = tid; i < 1600; i += 256)
      ws4[i] = *(const float4*)(w1 + (i / 20) * 160 + c0 + (i % 20) * 4);
    __syncthreads();
    if (tid < 240) {
      float acc[4][4] = {};
      #pragma unroll
      for (int iq = 0; iq < 20; iq++) {
        float4 xv[4], wv[4];
        #pragma unroll
        for (int dt = 0; dt < 4; dt++) xv[dt] = xs4[(t0 + dt) * 20 + iq];
        #pragma unroll
        for (int di = 0; di < 4; di++) wv[di] = ws4[(iq * 4 + di) * 20 + cg];
        #pragma unroll
        for (int dt = 0; dt < 4; dt++) {
          const float* xp = (const float*)&xv[dt];
          #pragma unroll
          for (int di = 0; di < 4; di++) {
            const float* wp = (const float*)&wv[di];
            #pragma unroll
            for (int dc = 0; dc < 4; dc++) acc[dt][dc] += xp[di] * wp[dc];
          }
        }
      }
      float4 bb = *(const float4*)(b1 + c0 + cg * 4);
      const float* bp = (const float*)&bb;
      #pragma unroll
      for (int dt = 0; dt < 4; dt++) {
        float4 out;
        float* op = (float*)&out;
        #pragma unroll
        for (int dc = 0; dc < 4; dc++) {
          float a = acc[dt][dc] + bp[dc];
          op[dc] = 0.5f * a * (1.0f + erff(a * 0.70710678118654752f));
        }
        *(float4*)(hb + (size_t)(tok0 + t0 + dt) * 160 + c0 + cg * 4) = out;
      }
    }
  }
}

// ---------------------------------------------------------------------------
// K4b: x = LN(x + H @ W2 + b2)  — 48 tokens/block, K chunked by 40
// ---------------------------------------------------------------------------
__global__ __launch_bounds__(256) void k_ffn2(
    const float* __restrict__ hb, const float* __restrict__ w2,
    const float* __restrict__ b2, const float* __restrict__ g,
    const float* __restrict__ be, float* __restrict__ x) {
  int tok0 = blockIdx.x * 48, tid = threadIdx.x;
  __shared__ __align__(16) float hs[48 * 160];
  __shared__ __align__(16) float ws[40 * 80];
  __shared__ float mstd[96];
  float4* hs4 = (float4*)hs;
  const float4* hb4 = (const float4*)(hb + (size_t)tok0 * 160);
  for (int i = tid; i < 1920; i += 256) hs4[i] = hb4[i];
  float4* ws4 = (float4*)ws;
  int tg = tid / 20, cg = tid % 20, t0 = tg * 4;
  float acc[4][4] = {};

  for (int k0 = 0; k0 < 160; k0 += 40) {
    __syncthreads();
    for (int i = tid; i < 800; i += 256)
      ws4[i] = *(const float4*)(w2 + (size_t)(k0 + i / 20) * 80 + (i % 20) * 4);
    __syncthreads();
    if (tid < 240) {
      #pragma unroll
      for (int iq = 0; iq < 10; iq++) {
        float4 xv[4], wv[4];
        #pragma unroll
        for (int dt = 0; dt < 4; dt++) xv[dt] = hs4[(t0 + dt) * 40 + k0 / 4 + iq];
        #pragma unroll
        for (int di = 0; di < 4; di++) wv[di] = ws4[(iq * 4 + di) * 20 + cg];
        #pragma unroll
        for (int dt = 0; dt < 4; dt++) {
          const float* xp = (const float*)&xv[dt];
          #pragma unroll
          for (int di = 0; di < 4; di++) {
            const float* wp = (const float*)&wv[di];
            #pragma unroll
            for (int dc = 0; dc < 4; dc++) acc[dt][dc] += xp[di] * wp[dc];
          }
        }
      }
    }
  }
  __syncthreads();   // hs GEMM reads done; reuse start of hs as y-buffer
  if (tid < 240) {
    float4 bb = *(const float4*)(b2 + cg * 4);
    const float* bp = (const float*)&bb;
    #pragma unroll
    for (int dt = 0; dt < 4; dt++) {
      float4 xr = *(const float4*)(x + (size_t)(tok0 + t0 + dt) * 80 + cg * 4);
      const float* xrp = (const float*)&xr;
      float4 out;
      out.x = acc[dt][0] + bp[0] + xrp[0];
      out.y = acc[dt][1] + bp[1] + xrp[1];
      out.z = acc[dt][2] + bp[2] + xrp[2];
      out.w = acc[dt][3] + bp[3] + xrp[3];
      hs4[(t0 + dt) * 20 + cg] = out;
    }
  }
  __syncthreads();
  if (tid < 48) {
    float s = 0.0f, s2 = 0.0f;
    #pragma unroll
    for (int iq = 0; iq < 20; iq++) {
      float4 v = hs4[tid * 20 + iq];
      s  += v.x + v.y + v.z + v.w;
      s2 += v.x * v.x + v.y * v.y + v.z * v.z + v.w * v.w;
    }
    float mean = s / 80.0f;
    float var  = fmaxf(s2 / 80.0f - mean * mean, 0.0f);
    mstd[tid] = mean; mstd[48 + tid] = rsqrtf(var + 1e-5f);
  }
  __syncthreads();
  for (int e = tid; e < 960; e += 256) {
    int t = e / 20, c4 = e % 20;
    float4 v = hs4[e];
    float4 gg = *(const float4*)(g + c4 * 4);
    float4 bb = *(const float4*)(be + c4 * 4);
    float m = mstd[t], r = mstd[48 + t];
    float4 out;
    out.x = (v.x - m) * r * gg.x + bb.x;
    out.y = (v.y - m) * r * gg.y + bb.y;
    out.z = (v.z - m) * r * gg.z + bb.z;
    out.w = (v.w - m) * r * gg.w + bb.w;
    ((float4*)(x + (size_t)tok0 * 80))[e] = out;
  }
}

// ---------------------------------------------------------------------------
// K5: final LN at gathered position + fnorm + h1 = gelu(final@pr_w1+pr_b1)
// ---------------------------------------------------------------------------
__global__ __launch_bounds__(128) void k_final(
    const float* __restrict__ x, const int* __restrict__ seq_len,
    const float* __restrict__ fn_g, const float* __restrict__ fn_b,
    const float* __restrict__ pr_w1, const float* __restrict__ pr_b1,
    float* __restrict__ fnorm, float* __restrict__ h1) {
  int b = blockIdx.x, tid = threadIdx.x;
  __shared__ float red[128], red2[128];
  __shared__ float fbuf[DD];
  int t = seq_len[b] - 1; t = min(max(t, 0), LL - 1);
  float v = 0.0f;
  if (tid < DD) v = x[((size_t)b * LL + t) * DD + tid];
  red[tid]  = (tid < DD) ? v : 0.0f;
  red2[tid] = (tid < DD) ? v * v : 0.0f;
  __syncthreads();
  for (int s = 64; s > 0; s >>= 1) {
    if (tid < s) { red[tid] += red[tid + s]; red2[tid] += red2[tid + s]; }
    __syncthreads();
  }
  float mean = red[0] / DD;
  float var  = fmaxf(red2[0] / DD - mean * mean, 0.0f);
  float rstd = rsqrtf(var + 1e-5f);
  float f = 0.0f;
  if (tid < DD) { f = (v - mean) * rstd * fn_g[tid] + fn_b[tid]; fbuf[tid] = f; }
  __syncthreads();
  red[tid] = (tid < DD) ? f * f : 0.0f;
  __syncthreads();
  for (int s = 64; s > 0; s >>= 1) {
    if (tid < s) red[tid] += red[tid + s];
    __syncthreads();
  }
  float rn = 1.0f / fmaxf(sqrtf(red[0]), 1e-12f);
  if (tid < DD) {
    fnorm[(size_t)b * DD + tid] = f * rn;
    float gacc = pr_b1[tid];
    for (int i = 0; i < DD; i++) gacc += fbuf[i] * pr_w1[i * DD + tid];
    h1[(size_t)b * DD + tid] = 0.5f * gacc * (1.0f + erff(gacc * 0.70710678118654752f));
  }
}

// ---------------------------------------------------------------------------
// K6: normalize proto rows -> transposed pnormT[k][c] for coalesced logits
// ---------------------------------------------------------------------------
__global__ __launch_bounds__(128) void k_pnorm(
    const float* __restrict__ protos, float* __restrict__ pnormT) {
  int c = blockIdx.x, tid = threadIdx.x;
  __shared__ float red[128];
  float v = 0.0f;
  if (tid < DD) v = protos[(size_t)c * DD + tid];
  red[tid] = (tid < DD) ? v * v : 0.0f;
  __syncthreads();
  for (int s = 64; s > 0; s >>= 1) {
    if (tid < s) red[tid] += red[tid + s];
    __syncthreads();
  }
  float rn = 1.0f / fmaxf(sqrtf(red[0]), 1e-12f);
  if (tid < DD) pnormT[(size_t)tid * NLOC + c] = v * rn;
}

// ---------------------------------------------------------------------------
// K7: logits
// ---------------------------------------------------------------------------
__global__ __launch_bounds__(256) void k_logits(
    const float* __restrict__ h1, const float* __restrict__ fnorm,
    const float* __restrict__ pr_w2, const float* __restrict__ pr_b2,
    const float* __restrict__ pnormT, const float* __restrict__ temp,
    float* __restrict__ out) {
  int b = blockIdx.x / 5, cb = blockIdx.x % 5;
  int tid = threadIdx.x;
  int c = cb * 256 + tid;
  __shared__ float h1s[DD], fns[DD];
  if (tid < DD) { h1s[tid] = h1[(size_t)b * DD + tid]; fns[tid] = fnorm[(size_t)b * DD + tid]; }
  __syncthreads();
  if (c < NLOC) {
    float a1 = pr_b2[c], a2 = 0.0f;
    for (int k = 0; k < DD; k++) {
      a1 += h1s[k] * pr_w2[(size_t)k * NLOC + c];
      a2 += fns[k] * pnormT[(size_t)k * NLOC + c];
    }
    float tt = fminf(fmaxf(temp[0], 0.5f), 3.0f);
    out[(size_t)b * NLOC + c] = (0.5f * a1 + 7.5f * a2) / tt;
  }
}

// ---------------------------------------------------------------------------
extern "C" void kernel_launch(void* const* d_in, const int* in_sizes, int n_in,
                              void* d_out, int out_size, void* d_ws, size_t ws_size,
                              hipStream_t stream) {
  const int* loc_seq   = (const int*)d_in[0];
  const int* user_seq  = (const int*)d_in[1];
  const int* wk_seq    = (const int*)d_in[2];
  const int* sm_seq    = (const int*)d_in[3];
  const int* dur_seq   = (const int*)d_in[4];
  const int* diff_seq  = (const int*)d_in[5];
  const int* seq_len   = (const int*)d_in[6];
  const float* loc_table = (const float*)d_in[7];
  const float* user_table= (const float*)d_in[8];
  const float* wk_table  = (const float*)d_in[9];
  const float* hr_table  = (const float*)d_in[10];
  const float* in_w   = (const float*)d_in[11];
  const float* in_b   = (const float*)d_in[12];
  const float* in_g   = (const float*)d_in[13];
  const float* in_be  = (const float*)d_in[14];
  const float* pos_emb= (const float*)d_in[15];
  const float* qkv_w  = (const float*)d_in[16];
  const float* proj_w = (const float*)d_in[17];
  const float* proj_b = (const float*)d_in[18];
  const float* rel_emb= (const float*)d_in[19];
  const float* n1_g   = (const float*)d_in[20];
  const float* n1_b   = (const float*)d_in[21];
  const float* ffn_w1 = (const float*)d_in[22];
  const float* ffn_b1 = (const float*)d_in[23];
  const float* ffn_w2 = (const float*)d_in[24];
  const float* ffn_b2 = (const float*)d_in[25];
  const float* n2_g   = (const float*)d_in[26];
  const float* n2_b   = (const float*)d_in[27];
  const float* fn_g   = (const float*)d_in[28];
  const float* fn_b   = (const float*)d_in[29];
  const float* pr_w1  = (const float*)d_in[30];
  const float* pr_b1  = (const float*)d_in[31];
  const float* pr_w2  = (const float*)d_in[32];
  const float* pr_b2  = (const float*)d_in[33];
  const float* protos = (const float*)d_in[34];
  const float* temp   = (const float*)d_in[35];
  float* out = (float*)d_out;

  // workspace layout (floats):
  // x: 9,830,400 | o: 9,830,400 | big(qkvo/hb shared): 29,491,200
  // fnorm: 163,840 | h1: 163,840 | pnormT: 94,960
  float* x      = (float*)d_ws;
  float* o      = x + (size_t)BB * LL * DD;
  float* big    = o + (size_t)BB * LL * DD;          // qkvo (B*14400) / hb (B*L*160)
  float* fnorm  = big + (size_t)BB * 14400;
  float* h1     = fnorm + (size_t)BB * DD;
  float* pnormT = h1 + (size_t)BB * DD;

  float* qkvo = big;
  float* hb   = big;

  k_embed<<<BB * LL, 128, 0, stream>>>(loc_seq, user_seq, wk_seq, sm_seq, dur_seq,
                                       diff_seq, loc_table, user_table, wk_table,
                                       hr_table, in_w, in_b, in_g, in_be, pos_emb, x);

  for (int l = 0; l < NLNUM; l++) {
    k_qkv<<<BB, 256, 0, stream>>>(x, qkv_w + (size_t)l * 80 * 240, qkvo);
    k_attn<<<BB * HH, 256, 0, stream>>>(qkvo, loc_seq,
                                        rel_emb + (size_t)l * RELN * HDD, o);
    k_proj_ln<<<BB * LL / 48, 256, 0, stream>>>(o, proj_w + (size_t)l * DD * DD,
                                                proj_b + (size_t)l * DD,
                                                n1_g + (size_t)l * DD,
                                                n1_b + (size_t)l * DD, x);
    k_ffn1<<<BB * LL / 48, 256, 0, stream>>>(x, ffn_w1 + (size_t)l * DD * DFF,
                                             ffn_b1 + (size_t)l * DFF, hb);
    k_ffn2<<<BB * LL / 48, 256, 0, stream>>>(hb, ffn_w2 + (size_t)l * DFF * DD,
                                             ffn_b2 + (size_t)l * DD,
                                             n2_g + (size_t)l * DD,
                                             n2_b + (size_t)l * DD, x);
  }

  k_pnorm<<<NLOC, 128, 0, stream>>>(protos, pnormT);
  k_final<<<BB, 128, 0, stream>>>(x, seq_len, fn_g, fn_b, pr_w1, pr_b1, fnorm, h1);
  k_logits<<<BB * 5, 256, 0, stream>>>(h1, fnorm, pr_w2, pr_b2, pnormT, temp, out);
}

// Round 3
// 2305.502 us; speedup vs baseline: 2.4065x; 2.0141x over previous
//
#include <hip/hip_runtime.h>
#include <hip/hip_bf16.h>
#include <math.h>

#define BB   2048
#define LL   60
#define DD   80
#define HH   8
#define HDD  10
#define NLNUM 3
#define NLOC 1187
#define DFF  160
#define IN_DIM 138
#define RELN 119

// Branchless gelu: erf via Abramowitz-Stegun 7.1.26 (|err| <= 1.5e-7).
// Avoids libm erff whose branchy inline blew k_ffn1 to 256 VGPRs + scratch
// spill (466 MB fetch / 871 MB write per dispatch in round 2).
__device__ __forceinline__ float gelu_f(float a) {
  float x = fabsf(a) * 0.70710678118654752f;
  float t = 1.0f / (1.0f + 0.3275911f * x);
  float y = t * (0.254829592f + t * (-0.284496736f + t * (1.421413741f +
            t * (-1.453152027f + t * 1.061405429f))));
  float e = 1.0f - y * __expf(-x * x);           // erf(|x|)
  float erf_s = copysignf(e, a);
  return 0.5f * a * (1.0f + erf_s);
}

// ---------------------------------------------------------------------------
// K1: embedding gather + input projection (138->80) + LayerNorm + pos_emb
// ---------------------------------------------------------------------------
__global__ __launch_bounds__(128) void k_embed(
    const int* __restrict__ loc_seq, const int* __restrict__ user_seq,
    const int* __restrict__ wk_seq, const int* __restrict__ sm_seq,
    const int* __restrict__ dur_seq, const int* __restrict__ diff_seq,
    const float* __restrict__ loc_table, const float* __restrict__ user_table,
    const float* __restrict__ wk_table, const float* __restrict__ hr_table,
    const float* __restrict__ in_w, const float* __restrict__ in_b,
    const float* __restrict__ in_g, const float* __restrict__ in_be,
    const float* __restrict__ pos_emb, float* __restrict__ x) {
  int tok = blockIdx.x;
  int t = tok % LL;
  int b = tok / LL;
  int tid = threadIdx.x;

  __shared__ __align__(16) float vin[IN_DIM];
  __shared__ float red[128];
  __shared__ float red2[128];

  int loc = loc_seq[tok];
  int usr = user_seq[b * LL];
  int wk  = wk_seq[tok];
  int hr  = sm_seq[tok] / 60; hr = min(max(hr, 0), 23);
  float dif = (float)diff_seq[tok] / 10.0f;
  float dur = (float)dur_seq[tok] / 300.0f;

  for (int i = tid; i < IN_DIM; i += 128) {
    float v;
    if (i < 80)        v = loc_table[(size_t)loc * 80 + i];
    else if (i < 104)  v = user_table[usr * 24 + (i - 80)];
    else if (i < 120)  v = wk_table[wk * 16 + (i - 104)];
    else if (i < 136)  v = hr_table[hr * 16 + (i - 120)];
    else if (i == 136) v = dif;
    else               v = dur;
    vin[i] = v;
  }
  __syncthreads();

  float acc = 0.0f;
  if (tid < DD) {
    acc = in_b[tid];
    for (int i = 0; i < IN_DIM; i++) acc += vin[i] * in_w[i * DD + tid];
  }
  red[tid]  = (tid < DD) ? acc : 0.0f;
  red2[tid] = (tid < DD) ? acc * acc : 0.0f;
  __syncthreads();
  for (int s = 64; s > 0; s >>= 1) {
    if (tid < s) { red[tid] += red[tid + s]; red2[tid] += red2[tid + s]; }
    __syncthreads();
  }
  float mean = red[0] / DD;
  float var  = fmaxf(red2[0] / DD - mean * mean, 0.0f);
  float rstd = rsqrtf(var + 1e-5f);
  if (tid < DD) {
    float y = (acc - mean) * rstd * in_g[tid] + in_be[tid] + pos_emb[t * DD + tid];
    x[(size_t)tok * DD + tid] = y;
  }
}

// ---------------------------------------------------------------------------
// K2a: qkv GEMM per batch row b: [60 x 80] @ [80 x 240] -> qkvo[b][c][t]
// ---------------------------------------------------------------------------
__global__ __launch_bounds__(256) void k_qkv(
    const float* __restrict__ x, const float* __restrict__ qkv_w,
    float* __restrict__ qkvo) {
  int b = blockIdx.x, tid = threadIdx.x;
  __shared__ __align__(16) float xs[LL * DD];
  __shared__ __align__(16) float ws[DD * DD];

  const float4* xb4 = (const float4*)(x + (size_t)b * LL * DD);
  float4* xs4 = (float4*)xs;
  for (int i = tid; i < LL * 20; i += 256) xs4[i] = xb4[i];
  float4* ws4 = (float4*)ws;

  for (int c0 = 0; c0 < 240; c0 += 80) {
    __syncthreads();
    for (int i = tid; i < 80 * 20; i += 256)
      ws4[i] = *(const float4*)(qkv_w + (i / 20) * 240 + c0 + (i % 20) * 4);
    __syncthreads();
    for (int slot = tid; slot < 300; slot += 256) {
      int tg = slot / 20, cg = slot % 20;
      int t0 = tg * 4;
      float acc[4][4] = {};
      #pragma unroll
      for (int iq = 0; iq < 20; iq++) {
        float4 xv[4], wv[4];
        #pragma unroll
        for (int dt = 0; dt < 4; dt++) xv[dt] = xs4[(t0 + dt) * 20 + iq];
        #pragma unroll
        for (int di = 0; di < 4; di++) wv[di] = ws4[(iq * 4 + di) * 20 + cg];
        #pragma unroll
        for (int dt = 0; dt < 4; dt++) {
          const float* xp = (const float*)&xv[dt];
          #pragma unroll
          for (int di = 0; di < 4; di++) {
            const float* wp = (const float*)&wv[di];
            #pragma unroll
            for (int dc = 0; dc < 4; dc++) acc[dt][dc] += xp[di] * wp[dc];
          }
        }
      }
      float* qb = qkvo + (size_t)b * 14400 + (size_t)(c0 + cg * 4) * 60 + t0;
      #pragma unroll
      for (int dc = 0; dc < 4; dc++)
        *(float4*)(qb + dc * 60) = make_float4(acc[0][dc], acc[1][dc], acc[2][dc], acc[3][dc]);
    }
  }
}

// ---------------------------------------------------------------------------
// K2b: attention per (b,h) reading precomputed qkv [b][c][t].
// ---------------------------------------------------------------------------
__global__ __launch_bounds__(256) void k_attn(
    const float* __restrict__ qkvo, const int* __restrict__ loc_seq,
    const float* __restrict__ rel_emb,
    float* __restrict__ o) {
  int bh = blockIdx.x;
  int b = bh >> 3, h = bh & 7;
  int tid = threadIdx.x;

  __shared__ __align__(16) float qs[HDD * 60];
  __shared__ __align__(16) float ks[HDD * 60];
  __shared__ __align__(16) float vs[HDD * 60];
  __shared__ __align__(16) float relT[HDD * 120];
  __shared__ __align__(16) float sc[60 * 64];
  __shared__ float msk[60];

  const float4* src = (const float4*)(qkvo + (size_t)b * 14400);
  float4* q4 = (float4*)qs; float4* k4 = (float4*)ks; float4* v4 = (float4*)vs;
  for (int i = tid; i < 150; i += 256) {
    q4[i] = src[h * 150 + i];
    k4[i] = src[1200 + h * 150 + i];
    v4[i] = src[2400 + h * 150 + i];
  }
  for (int i = tid; i < RELN * HDD; i += 256) {
    int p = i / 10, d = i % 10;
    relT[d * 120 + p] = rel_emb[i];
  }
  if (tid < 60) msk[tid] = (loc_seq[b * LL + tid] == 0) ? 1.0f : 0.0f;
  __syncthreads();

  if (tid < 225) {
    int ig = tid / 15, jg = tid % 15;
    int i0 = ig * 4, j0 = jg * 4;
    int w0 = j0 - i0 + 56;
    float acc[4][4] = {};
    #pragma unroll
    for (int d = 0; d < 10; d++) {
      float4 qv = *(const float4*)(qs + d * 60 + i0);
      float4 kv = *(const float4*)(ks + d * 60 + j0);
      float4 rA = *(const float4*)(relT + d * 120 + w0);
      float4 rB = *(const float4*)(relT + d * 120 + w0 + 4);
      float rr[8] = {rA.x, rA.y, rA.z, rA.w, rB.x, rB.y, rB.z, rB.w};
      const float* qp = (const float*)&qv;
      const float* kp = (const float*)&kv;
      #pragma unroll
      for (int di = 0; di < 4; di++)
        #pragma unroll
        for (int dj = 0; dj < 4; dj++)
          acc[di][dj] += qp[di] * (kp[dj] + rr[dj - di + 3]);
    }
    const float scale = 0.31622776601683794f;
    #pragma unroll
    for (int di = 0; di < 4; di++) {
      #pragma unroll
      for (int dj = 0; dj < 4; dj++) {
        float v = acc[di][dj] * scale;
        if (msk[j0 + dj] != 0.0f) v = -1e30f;
        acc[di][dj] = v;
      }
      *(float4*)(sc + (i0 + di) * 64 + j0) =
          make_float4(acc[di][0], acc[di][1], acc[di][2], acc[di][3]);
    }
  }
  __syncthreads();

  int wid = tid >> 6, lane = tid & 63;
  for (int i = wid; i < 60; i += 4) {
    float v = (lane < 60) ? sc[i * 64 + lane] : -3.0e38f;
    float m = v;
    #pragma unroll
    for (int s = 32; s > 0; s >>= 1) m = fmaxf(m, __shfl_xor(m, s));
    float e = (lane < 60) ? __expf(v - m) : 0.0f;
    float sum = e;
    #pragma unroll
    for (int s = 32; s > 0; s >>= 1) sum += __shfl_xor(sum, s);
    if (lane < 60) sc[i * 64 + lane] = e / sum;
  }
  __syncthreads();

  if (tid < 150) {
    int ig = tid / 10, d = tid % 10;
    int i0 = ig * 4;
    float acc[4] = {0, 0, 0, 0};
    #pragma unroll
    for (int jq = 0; jq < 15; jq++) {
      float4 vv = *(const float4*)(vs + d * 60 + jq * 4);
      #pragma unroll
      for (int di = 0; di < 4; di++) {
        float4 av = *(const float4*)(sc + (i0 + di) * 64 + jq * 4);
        acc[di] += av.x * vv.x + av.y * vv.y + av.z * vv.z + av.w * vv.w;
      }
    }
    #pragma unroll
    for (int di = 0; di < 4; di++)
      o[((size_t)b * 60 + i0 + di) * 80 + h * 10 + d] = acc[di];
  }
}

// ---------------------------------------------------------------------------
// K3: x = LN(x + o @ proj_w + proj_b)  — 48 tokens/block
// ---------------------------------------------------------------------------
__global__ __launch_bounds__(256) void k_proj_ln(
    const float* __restrict__ o, const float* __restrict__ proj_w,
    const float* __restrict__ proj_b, const float* __restrict__ g,
    const float* __restrict__ be, float* __restrict__ x) {
  int tok0 = blockIdx.x * 48, tid = threadIdx.x;
  __shared__ __align__(16) float os[48 * 80];
  __shared__ __align__(16) float ws[80 * 80];
  __shared__ float mstd[96];

  float4* os4 = (float4*)os;
  const float4* ob4 = (const float4*)(o + (size_t)tok0 * 80);
  for (int i = tid; i < 960; i += 256) os4[i] = ob4[i];
  float4* ws4 = (float4*)ws;
  for (int i = tid; i < 1600; i += 256)
    ws4[i] = *(const float4*)(proj_w + (i / 20) * 80 + (i % 20) * 4);
  __syncthreads();

  int tg = tid / 20, cg = tid % 20, t0 = tg * 4;
  float acc[4][4] = {};
  if (tid < 240) {
    #pragma unroll
    for (int iq = 0; iq < 20; iq++) {
      float4 xv[4], wv[4];
      #pragma unroll
      for (int dt = 0; dt < 4; dt++) xv[dt] = os4[(t0 + dt) * 20 + iq];
      #pragma unroll
      for (int di = 0; di < 4; di++) wv[di] = ws4[(iq * 4 + di) * 20 + cg];
      #pragma unroll
      for (int dt = 0; dt < 4; dt++) {
        const float* xp = (const float*)&xv[dt];
        #pragma unroll
        for (int di = 0; di < 4; di++) {
          const float* wp = (const float*)&wv[di];
          #pragma unroll
          for (int dc = 0; dc < 4; dc++) acc[dt][dc] += xp[di] * wp[dc];
        }
      }
    }
  }
  __syncthreads();
  if (tid < 240) {
    float4 pb = *(const float4*)(proj_b + cg * 4);
    const float* pbp = (const float*)&pb;
    #pragma unroll
    for (int dt = 0; dt < 4; dt++) {
      float4 xr = *(const float4*)(x + (size_t)(tok0 + t0 + dt) * 80 + cg * 4);
      const float* xrp = (const float*)&xr;
      float4 out;
      out.x = acc[dt][0] + pbp[0] + xrp[0];
      out.y = acc[dt][1] + pbp[1] + xrp[1];
      out.z = acc[dt][2] + pbp[2] + xrp[2];
      out.w = acc[dt][3] + pbp[3] + xrp[3];
      os4[(t0 + dt) * 20 + cg] = out;
    }
  }
  __syncthreads();
  if (tid < 48) {
    float s = 0.0f, s2 = 0.0f;
    #pragma unroll
    for (int iq = 0; iq < 20; iq++) {
      float4 v = os4[tid * 20 + iq];
      s  += v.x + v.y + v.z + v.w;
      s2 += v.x * v.x + v.y * v.y + v.z * v.z + v.w * v.w;
    }
    float mean = s / 80.0f;
    float var  = fmaxf(s2 / 80.0f - mean * mean, 0.0f);
    mstd[tid] = mean; mstd[48 + tid] = rsqrtf(var + 1e-5f);
  }
  __syncthreads();
  for (int e = tid; e < 960; e += 256) {
    int t = e / 20, c4 = e % 20;
    float4 v = os4[e];
    float4 gg = *(const float4*)(g + c4 * 4);
    float4 bb = *(const float4*)(be + c4 * 4);
    float m = mstd[t], r = mstd[48 + t];
    float4 out;
    out.x = (v.x - m) * r * gg.x + bb.x;
    out.y = (v.y - m) * r * gg.y + bb.y;
    out.z = (v.z - m) * r * gg.z + bb.z;
    out.w = (v.w - m) * r * gg.w + bb.w;
    ((float4*)(x + (size_t)tok0 * 80))[e] = out;
  }
}

// ---------------------------------------------------------------------------
// K4: fused FFN: x = LN(x + W2ᵀgelu(W1ᵀx + b1) + b2)  — 48 tokens/block
// h lives entirely in LDS; residual comes from the staged xs tile.
// ---------------------------------------------------------------------------
__global__ __launch_bounds__(256) void k_ffn(
    const float* __restrict__ w1, const float* __restrict__ b1,
    const float* __restrict__ w2, const float* __restrict__ b2,
    const float* __restrict__ g, const float* __restrict__ be,
    float* __restrict__ x) {
  int tok0 = blockIdx.x * 48, tid = threadIdx.x;
  __shared__ __align__(16) float xs[48 * 80];    // input rows (kept for residual)
  __shared__ __align__(16) float hs[48 * 160];   // hidden after gelu
  __shared__ __align__(16) float ws[80 * 80];    // weight chunk
  __shared__ float mstd[96];

  float4* xs4 = (float4*)xs;
  float4* hs4 = (float4*)hs;
  float4* ws4 = (float4*)ws;
  const float4* xb4 = (const float4*)(x + (size_t)tok0 * 80);
  for (int i = tid; i < 960; i += 256) xs4[i] = xb4[i];

  int tg = tid / 20, cg = tid % 20, t0 = tg * 4;

  // phase A: h = gelu(x @ w1 + b1), col chunks of 80
  for (int c0 = 0; c0 < 160; c0 += 80) {
    __syncthreads();
    for (int i = tid; i < 1600; i += 256)
      ws4[i] = *(const float4*)(w1 + (i / 20) * 160 + c0 + (i % 20) * 4);
    __syncthreads();
    if (tid < 240) {
      float acc[4][4] = {};
      #pragma unroll
      for (int iq = 0; iq < 20; iq++) {
        float4 xv[4], wv[4];
        #pragma unroll
        for (int dt = 0; dt < 4; dt++) xv[dt] = xs4[(t0 + dt) * 20 + iq];
        #pragma unroll
        for (int di = 0; di < 4; di++) wv[di] = ws4[(iq * 4 + di) * 20 + cg];
        #pragma unroll
        for (int dt = 0; dt < 4; dt++) {
          const float* xp = (const float*)&xv[dt];
          #pragma unroll
          for (int di = 0; di < 4; di++) {
            const float* wp = (const float*)&wv[di];
            #pragma unroll
            for (int dc = 0; dc < 4; dc++) acc[dt][dc] += xp[di] * wp[dc];
          }
        }
      }
      float4 bb = *(const float4*)(b1 + c0 + cg * 4);
      const float* bp = (const float*)&bb;
      #pragma unroll
      for (int dt = 0; dt < 4; dt++) {
        float4 out;
        float* op = (float*)&out;
        #pragma unroll
        for (int dc = 0; dc < 4; dc++)
          op[dc] = gelu_f(acc[dt][dc] + bp[dc]);
        hs4[(t0 + dt) * 40 + c0 / 4 + cg] = out;
      }
    }
  }

  // phase B: y = h @ w2 + b2 + xres, k chunks of 80
  float acc[4][4] = {};
  for (int k0 = 0; k0 < 160; k0 += 80) {
    __syncthreads();
    for (int i = tid; i < 1600; i += 256)
      ws4[i] = *(const float4*)(w2 + (size_t)(k0 + i / 20) * 80 + (i % 20) * 4);
    __syncthreads();
    if (tid < 240) {
      #pragma unroll
      for (int iq = 0; iq < 20; iq++) {
        float4 hv[4], wv[4];
        #pragma unroll
        for (int dt = 0; dt < 4; dt++) hv[dt] = hs4[(t0 + dt) * 40 + k0 / 4 + iq];
        #pragma unroll
        for (int di = 0; di < 4; di++) wv[di] = ws4[(iq * 4 + di) * 20 + cg];
        #pragma unroll
        for (int dt = 0; dt < 4; dt++) {
          const float* hp = (const float*)&hv[dt];
          #pragma unroll
          for (int di = 0; di < 4; di++) {
            const float* wp = (const float*)&wv[di];
            #pragma unroll
            for (int dc = 0; dc < 4; dc++) acc[dt][dc] += hp[di] * wp[dc];
          }
        }
      }
    }
  }
  __syncthreads();   // hs readers done; reuse hs front as y-buffer
  if (tid < 240) {
    float4 bb = *(const float4*)(b2 + cg * 4);
    const float* bp = (const float*)&bb;
    #pragma unroll
    for (int dt = 0; dt < 4; dt++) {
      float4 xr = xs4[(t0 + dt) * 20 + cg];   // residual from LDS
      const float* xrp = (const float*)&xr;
      float4 out;
      out.x = acc[dt][0] + bp[0] + xrp[0];
      out.y = acc[dt][1] + bp[1] + xrp[1];
      out.z = acc[dt][2] + bp[2] + xrp[2];
      out.w = acc[dt][3] + bp[3] + xrp[3];
      hs4[(t0 + dt) * 20 + cg] = out;
    }
  }
  __syncthreads();
  if (tid < 48) {
    float s = 0.0f, s2 = 0.0f;
    #pragma unroll
    for (int iq = 0; iq < 20; iq++) {
      float4 v = hs4[tid * 20 + iq];
      s  += v.x + v.y + v.z + v.w;
      s2 += v.x * v.x + v.y * v.y + v.z * v.z + v.w * v.w;
    }
    float mean = s / 80.0f;
    float var  = fmaxf(s2 / 80.0f - mean * mean, 0.0f);
    mstd[tid] = mean; mstd[48 + tid] = rsqrtf(var + 1e-5f);
  }
  __syncthreads();
  for (int e = tid; e < 960; e += 256) {
    int t = e / 20, c4 = e % 20;
    float4 v = hs4[e];
    float4 gg = *(const float4*)(g + c4 * 4);
    float4 bb = *(const float4*)(be + c4 * 4);
    float m = mstd[t], r = mstd[48 + t];
    float4 out;
    out.x = (v.x - m) * r * gg.x + bb.x;
    out.y = (v.y - m) * r * gg.y + bb.y;
    out.z = (v.z - m) * r * gg.z + bb.z;
    out.w = (v.w - m) * r * gg.w + bb.w;
    ((float4*)(x + (size_t)tok0 * 80))[e] = out;
  }
}

// ---------------------------------------------------------------------------
// K5: final LN at gathered position + fnorm + h1 = gelu(final@pr_w1+pr_b1)
// ---------------------------------------------------------------------------
__global__ __launch_bounds__(128) void k_final(
    const float* __restrict__ x, const int* __restrict__ seq_len,
    const float* __restrict__ fn_g, const float* __restrict__ fn_b,
    const float* __restrict__ pr_w1, const float* __restrict__ pr_b1,
    float* __restrict__ fnorm, float* __restrict__ h1) {
  int b = blockIdx.x, tid = threadIdx.x;
  __shared__ float red[128], red2[128];
  __shared__ float fbuf[DD];
  int t = seq_len[b] - 1; t = min(max(t, 0), LL - 1);
  float v = 0.0f;
  if (tid < DD) v = x[((size_t)b * LL + t) * DD + tid];
  red[tid]  = (tid < DD) ? v : 0.0f;
  red2[tid] = (tid < DD) ? v * v : 0.0f;
  __syncthreads();
  for (int s = 64; s > 0; s >>= 1) {
    if (tid < s) { red[tid] += red[tid + s]; red2[tid] += red2[tid + s]; }
    __syncthreads();
  }
  float mean = red[0] / DD;
  float var  = fmaxf(red2[0] / DD - mean * mean, 0.0f);
  float rstd = rsqrtf(var + 1e-5f);
  float f = 0.0f;
  if (tid < DD) { f = (v - mean) * rstd * fn_g[tid] + fn_b[tid]; fbuf[tid] = f; }
  __syncthreads();
  red[tid] = (tid < DD) ? f * f : 0.0f;
  __syncthreads();
  for (int s = 64; s > 0; s >>= 1) {
    if (tid < s) red[tid] += red[tid + s];
    __syncthreads();
  }
  float rn = 1.0f / fmaxf(sqrtf(red[0]), 1e-12f);
  if (tid < DD) {
    fnorm[(size_t)b * DD + tid] = f * rn;
    float gacc = pr_b1[tid];
    for (int i = 0; i < DD; i++) gacc += fbuf[i] * pr_w1[i * DD + tid];
    h1[(size_t)b * DD + tid] = gelu_f(gacc);
  }
}

// ---------------------------------------------------------------------------
// K6: normalize proto rows -> transposed pnormT[k][c]
// ---------------------------------------------------------------------------
__global__ __launch_bounds__(128) void k_pnorm(
    const float* __restrict__ protos, float* __restrict__ pnormT) {
  int c = blockIdx.x, tid = threadIdx.x;
  __shared__ float red[128];
  float v = 0.0f;
  if (tid < DD) v = protos[(size_t)c * DD + tid];
  red[tid] = (tid < DD) ? v * v : 0.0f;
  __syncthreads();
  for (int s = 64; s > 0; s >>= 1) {
    if (tid < s) red[tid] += red[tid + s];
    __syncthreads();
  }
  float rn = 1.0f / fmaxf(sqrtf(red[0]), 1e-12f);
  if (tid < DD) pnormT[(size_t)tid * NLOC + c] = v * rn;
}

// ---------------------------------------------------------------------------
// K7: logits
// ---------------------------------------------------------------------------
__global__ __launch_bounds__(256) void k_logits(
    const float* __restrict__ h1, const float* __restrict__ fnorm,
    const float* __restrict__ pr_w2, const float* __restrict__ pr_b2,
    const float* __restrict__ pnormT, const float* __restrict__ temp,
    float* __restrict__ out) {
  int b = blockIdx.x / 5, cb = blockIdx.x % 5;
  int tid = threadIdx.x;
  int c = cb * 256 + tid;
  __shared__ float h1s[DD], fns[DD];
  if (tid < DD) { h1s[tid] = h1[(size_t)b * DD + tid]; fns[tid] = fnorm[(size_t)b * DD + tid]; }
  __syncthreads();
  if (c < NLOC) {
    float a1 = pr_b2[c], a2 = 0.0f;
    for (int k = 0; k < DD; k++) {
      a1 += h1s[k] * pr_w2[(size_t)k * NLOC + c];
      a2 += fns[k] * pnormT[(size_t)k * NLOC + c];
    }
    float tt = fminf(fmaxf(temp[0], 0.5f), 3.0f);
    out[(size_t)b * NLOC + c] = (0.5f * a1 + 7.5f * a2) / tt;
  }
}

// ---------------------------------------------------------------------------
extern "C" void kernel_launch(void* const* d_in, const int* in_sizes, int n_in,
                              void* d_out, int out_size, void* d_ws, size_t ws_size,
                              hipStream_t stream) {
  const int* loc_seq   = (const int*)d_in[0];
  const int* user_seq  = (const int*)d_in[1];
  const int* wk_seq    = (const int*)d_in[2];
  const int* sm_seq    = (const int*)d_in[3];
  const int* dur_seq   = (const int*)d_in[4];
  const int* diff_seq  = (const int*)d_in[5];
  const int* seq_len   = (const int*)d_in[6];
  const float* loc_table = (const float*)d_in[7];
  const float* user_table= (const float*)d_in[8];
  const float* wk_table  = (const float*)d_in[9];
  const float* hr_table  = (const float*)d_in[10];
  const float* in_w   = (const float*)d_in[11];
  const float* in_b   = (const float*)d_in[12];
  const float* in_g   = (const float*)d_in[13];
  const float* in_be  = (const float*)d_in[14];
  const float* pos_emb= (const float*)d_in[15];
  const float* qkv_w  = (const float*)d_in[16];
  const float* proj_w = (const float*)d_in[17];
  const float* proj_b = (const float*)d_in[18];
  const float* rel_emb= (const float*)d_in[19];
  const float* n1_g   = (const float*)d_in[20];
  const float* n1_b   = (const float*)d_in[21];
  const float* ffn_w1 = (const float*)d_in[22];
  const float* ffn_b1 = (const float*)d_in[23];
  const float* ffn_w2 = (const float*)d_in[24];
  const float* ffn_b2 = (const float*)d_in[25];
  const float* n2_g   = (const float*)d_in[26];
  const float* n2_b   = (const float*)d_in[27];
  const float* fn_g   = (const float*)d_in[28];
  const float* fn_b   = (const float*)d_in[29];
  const float* pr_w1  = (const float*)d_in[30];
  const float* pr_b1  = (const float*)d_in[31];
  const float* pr_w2  = (const float*)d_in[32];
  const float* pr_b2  = (const float*)d_in[33];
  const float* protos = (const float*)d_in[34];
  const float* temp   = (const float*)d_in[35];
  float* out = (float*)d_out;

  float* x      = (float*)d_ws;
  float* o      = x + (size_t)BB * LL * DD;
  float* qkvo   = o + (size_t)BB * LL * DD;
  float* fnorm  = qkvo + (size_t)BB * 14400;
  float* h1     = fnorm + (size_t)BB * DD;
  float* pnormT = h1 + (size_t)BB * DD;

  k_embed<<<BB * LL, 128, 0, stream>>>(loc_seq, user_seq, wk_seq, sm_seq, dur_seq,
                                       diff_seq, loc_table, user_table, wk_table,
                                       hr_table, in_w, in_b, in_g, in_be, pos_emb, x);

  for (int l = 0; l < NLNUM; l++) {
    k_qkv<<<BB, 256, 0, stream>>>(x, qkv_w + (size_t)l * 80 * 240, qkvo);
    k_attn<<<BB * HH, 256, 0, stream>>>(qkvo, loc_seq,
                                        rel_emb + (size_t)l * RELN * HDD, o);
    k_proj_ln<<<BB * LL / 48, 256, 0, stream>>>(o, proj_w + (size_t)l * DD * DD,
                                                proj_b + (size_t)l * DD,
                                                n1_g + (size_t)l * DD,
                                                n1_b + (size_t)l * DD, x);
    k_ffn<<<BB * LL / 48, 256, 0, stream>>>(ffn_w1 + (size_t)l * DD * DFF,
                                            ffn_b1 + (size_t)l * DFF,
                                            ffn_w2 + (size_t)l * DFF * DD,
                                            ffn_b2 + (size_t)l * DD,
                                            n2_g + (size_t)l * DD,
                                            n2_b + (size_t)l * DD, x);
  }

  k_pnorm<<<NLOC, 128, 0, stream>>>(protos, pnormT);
  k_final<<<BB, 128, 0, stream>>>(x, seq_len, fn_g, fn_b, pr_w1, pr_b1, fnorm, h1);
  k_logits<<<BB * 5, 256, 0, stream>>>(h1, fnorm, pr_w2, pr_b2, pnormT, temp, out);
}